// Round 12
// baseline (210.927 us; speedup 1.0000x reference)
//
#include <hip/hip_runtime.h>

constexpr int HID = 64;
constexpr int RB = 128;        // mm block row-tile
constexpr int KC = 32;         // mm K-chunk
constexpr int NPB = 128;       // nodes per bucket (pow2: bucket = dst >> 7)
constexpr int MAXBUCK = 512;   // supports nN <= 65536
constexpr int CAP = 2560;      // pair slots per bucket (mean 2048 + 11 sigma)
constexpr int CHUNK = 2048;    // edges per k_bucket block (391 blocks)

// ---- CSR build pass 1: append (src,dst) pairs into fixed-capacity bucket
// regions. Block-level LDS histogram + one global reservation per
// (block,bucket) keeps each reserved range single-owner -> coalesced. ----
__global__ __launch_bounds__(256) void k_bucket(const int* __restrict__ src,
                                                const int* __restrict__ dst, int nE,
                                                int* __restrict__ bcursor,
                                                int2* __restrict__ pairs, int nBuck) {
  __shared__ int hist[MAXBUCK];
  __shared__ int base[MAXBUCK];
  const int t = threadIdx.x;
  const int e0 = blockIdx.x * CHUNK;
  const int eEnd = min(e0 + CHUNK, nE);
  for (int i = t; i < nBuck; i += 256) hist[i] = 0;
  __syncthreads();
  for (int e = e0 + t; e < eEnd; e += 256)
    atomicAdd(&hist[dst[e] >> 7], 1);
  __syncthreads();
  for (int i = t; i < nBuck; i += 256) {
    int c = hist[i];
    int r = (c > 0) ? atomicAdd(&bcursor[i], c) : 0;
    base[i] = i * CAP + r;
    hist[i] = 0;
  }
  __syncthreads();
  for (int e = e0 + t; e < eEnd; e += 256) {
    int d = dst[e];
    int b = d >> 7;
    int idx = atomicAdd(&hist[b], 1);
    pairs[base[b] + idx] = make_int2(src[e], d);
  }
}

// ---- CSR build pass 2: one block per bucket. LDS histogram -> per-node deg,
// LDS scan -> row bounds + dinv, then local scatter of csr. ----
__global__ __launch_bounds__(256) void k_place(const int2* __restrict__ pairs,
                                               const int* __restrict__ bcursor,
                                               int* __restrict__ csr,
                                               int* __restrict__ row_lo,
                                               int* __restrict__ row_hi,
                                               float* __restrict__ dinv, int nN) {
  __shared__ int cnt[NPB], sc[NPB], cur[NPB];
  const int t = threadIdx.x;
  const int b = blockIdx.x;
  const int vbase = b * NPB;
  const int lo = b * CAP;
  const int npairs = bcursor[b];
  if (t < NPB) cnt[t] = 0;
  __syncthreads();
  for (int p = t; p < npairs; p += 256)
    atomicAdd(&cnt[pairs[lo + p].y - vbase], 1);
  __syncthreads();
  if (t < NPB) sc[t] = cnt[t];
  __syncthreads();
  for (int d = 1; d < NPB; d <<= 1) {
    int x = 0;
    if (t < NPB) { x = sc[t]; if (t >= d) x += sc[t - d]; }
    __syncthreads();
    if (t < NPB) sc[t] = x;
    __syncthreads();
  }
  if (t < NPB && vbase + t < nN) {
    int ex = sc[t] - cnt[t];
    row_lo[vbase + t] = lo + ex;
    row_hi[vbase + t] = lo + sc[t];
    dinv[vbase + t] = rsqrtf((float)cnt[t] + 1.0f);   // +1 = self-loop
    cur[t] = lo + ex;
  }
  __syncthreads();
  for (int p = t; p < npairs; p += 256) {
    int2 e = pairs[lo + p];
    int pos = atomicAdd(&cur[e.y - vbase], 1);
    csr[pos] = e.x;
  }
}

// ---- LDS-tiled matmul + row scale: out[v,c] = dinv[v] * sum_k X[v,k]*W[k,c] ----
template <int K>
__global__ __launch_bounds__(256) void k_mm_tile(const float* __restrict__ X,
                                                 const float* __restrict__ W,
                                                 const float* __restrict__ dinv,
                                                 float* __restrict__ out, int nRows) {
  __shared__ float Xs[RB][KC + 1];
  __shared__ float Ws[KC][HID];

  const int t    = threadIdx.x;
  const int lane = t & 63;
  const int wid  = t >> 6;
  const int rg   = lane >> 3;
  const int cg   = lane & 7;
  const int rb   = blockIdx.x * RB;
  const int rloc = wid * 32 + rg * 4;

  float acc[4][8];
#pragma unroll
  for (int i = 0; i < 4; ++i)
#pragma unroll
    for (int j = 0; j < 8; ++j) acc[i][j] = 0.f;

  for (int c = 0; c < K / KC; ++c) {
    const int k0 = c * KC;
    {
      const int r  = t >> 1;
      const int kh = (t & 1) * 16;
      const int grow = rb + r;
      if (grow < nRows) {
        const float* p = X + (size_t)grow * K + k0 + kh;
#pragma unroll
        for (int q = 0; q < 4; ++q) {
          const float4 v = *(const float4*)(p + q * 4);
          float* d = &Xs[r][kh + q * 4];
          d[0] = v.x; d[1] = v.y; d[2] = v.z; d[3] = v.w;
        }
      }
    }
    {
      const float* p = W + (size_t)(k0 + (t >> 3)) * HID + (t & 7) * 8;
      const float4 v0 = *(const float4*)p;
      const float4 v1 = *(const float4*)(p + 4);
      float* d = &Ws[t >> 3][(t & 7) * 8];
      ((float4*)d)[0] = v0;
      ((float4*)d)[1] = v1;
    }
    __syncthreads();

#pragma unroll
    for (int k = 0; k < KC; ++k) {
      const float4 w0 = *(const float4*)&Ws[k][cg * 8];
      const float4 w1 = *(const float4*)&Ws[k][cg * 8 + 4];
      float xv[4];
#pragma unroll
      for (int i = 0; i < 4; ++i) xv[i] = Xs[rloc + i][k];
#pragma unroll
      for (int i = 0; i < 4; ++i) {
        acc[i][0] = fmaf(xv[i], w0.x, acc[i][0]);
        acc[i][1] = fmaf(xv[i], w0.y, acc[i][1]);
        acc[i][2] = fmaf(xv[i], w0.z, acc[i][2]);
        acc[i][3] = fmaf(xv[i], w0.w, acc[i][3]);
        acc[i][4] = fmaf(xv[i], w1.x, acc[i][4]);
        acc[i][5] = fmaf(xv[i], w1.y, acc[i][5]);
        acc[i][6] = fmaf(xv[i], w1.z, acc[i][6]);
        acc[i][7] = fmaf(xv[i], w1.w, acc[i][7]);
      }
    }
    __syncthreads();
  }

#pragma unroll
  for (int i = 0; i < 4; ++i) {
    const int row = rb + rloc + i;
    if (row < nRows) {
      const float s = dinv[row];
      float4 o0, o1;
      o0.x = acc[i][0] * s; o0.y = acc[i][1] * s; o0.z = acc[i][2] * s; o0.w = acc[i][3] * s;
      o1.x = acc[i][4] * s; o1.y = acc[i][5] * s; o1.z = acc[i][6] * s; o1.w = acc[i][7] * s;
      float* p = out + (size_t)row * HID + cg * 8;
      ((float4*)p)[0] = o0;
      ((float4*)p)[1] = o1;
    }
  }
}

// ---- gather core: 8-deep explicit load staging for MLP ----
// Per 16-edge batch: two half-batches of 8 rows; all 8 loads issued as a
// group into hb[] (independent), then accumulated. ~8 row-loads in flight
// per wave instead of the compiler's ~2-3 (VGPR_Count=32 evidence, r10).
#define GATHER_ACC_LOOP                                                        \
  int idxv = (cq < cnt) ? csr[lo + cq] : 0;                                    \
  for (int base = 0; base < cnt; base += 16) {                                 \
    const int nb = base + 16;                                                  \
    int nidx = (nb + cq < cnt) ? csr[lo + nb + cq] : 0;                        \
    _Pragma("unroll")                                                          \
    for (int half = 0; half < 2; ++half) {                                     \
      float4 hb[8];                                                            \
      _Pragma("unroll")                                                        \
      for (int j = 0; j < 8; ++j) {                                            \
        int s = __shfl(idxv, (ng << 4) + half * 8 + j, 64);                    \
        hb[j] = (base + half * 8 + j < cnt) ? H4[(size_t)s * 16 + cq]          \
                                            : make_float4(0.f, 0.f, 0.f, 0.f);\
      }                                                                        \
      _Pragma("unroll")                                                        \
      for (int j = 0; j < 8; ++j) {                                            \
        const int c = (half * 8 + j) & 3;                                      \
        acc[c][0] += (double)hb[j].x;                                          \
        acc[c][1] += (double)hb[j].y;                                          \
        acc[c][2] += (double)hb[j].z;                                          \
        acc[c][3] += (double)hb[j].w;                                          \
      }                                                                        \
    }                                                                          \
    idxv = nidx;                                                               \
  }

// ---- fused gather + epilogue + 64x64 matmul (layer1 agg + mm2) ----
__global__ __launch_bounds__(256) void k_gather_mm(const int* __restrict__ csr,
                                                   const int* __restrict__ row_lo,
                                                   const int* __restrict__ row_hi,
                                                   const float4* __restrict__ H4,
                                                   const float* __restrict__ dinv,
                                                   const float* __restrict__ b,
                                                   const float* __restrict__ W2,
                                                   float4* __restrict__ out4, int nN) {
  __shared__ float W2s[HID][HID];     // 16 KB
  __shared__ float z1s[16][68];       // padded

  const int t = threadIdx.x;
  for (int i = t; i < HID * HID / 4; i += 256)
    ((float4*)W2s)[i] = ((const float4*)W2)[i];
  __syncthreads();

  const int wid = t >> 6;
  const int lane = t & 63;
  const int ng = lane >> 4;
  const int cq = lane & 15;
  const int nl = wid * 4 + ng;
  const int v = blockIdx.x * 16 + nl;
  const int vv = min(v, nN - 1);
  const int lo = row_lo[vv];
  const int cnt = row_hi[vv] - lo;

  double acc[4][4];
#pragma unroll
  for (int c = 0; c < 4; ++c)
#pragma unroll
    for (int q = 0; q < 4; ++q) acc[c][q] = 0.0;
  {
    const float4 sv = H4[(size_t)vv * 16 + cq];   // self-loop
    acc[0][0] = (double)sv.x; acc[0][1] = (double)sv.y;
    acc[0][2] = (double)sv.z; acc[0][3] = (double)sv.w;
  }

  GATHER_ACC_LOOP

  // z1 = relu(dinv*gather + b1) -> LDS (wave-internal, no barrier)
  {
    const float dv = dinv[vv];
    const float4 bb = ((const float4*)b)[cq];
    float4 z;
    z.x = fmaxf(fmaf(dv, (float)((acc[0][0] + acc[1][0]) + (acc[2][0] + acc[3][0])), bb.x), 0.f);
    z.y = fmaxf(fmaf(dv, (float)((acc[0][1] + acc[1][1]) + (acc[2][1] + acc[3][1])), bb.y), 0.f);
    z.z = fmaxf(fmaf(dv, (float)((acc[0][2] + acc[1][2]) + (acc[2][2] + acc[3][2])), bb.z), 0.f);
    z.w = fmaxf(fmaf(dv, (float)((acc[0][3] + acc[1][3]) + (acc[2][3] + acc[3][3])), bb.w), 0.f);
    float* zp = &z1s[nl][cq * 4];
    zp[0] = z.x; zp[1] = z.y; zp[2] = z.z; zp[3] = z.w;
  }

  float h0 = 0.f, h1 = 0.f, h2 = 0.f, h3 = 0.f;
#pragma unroll 8
  for (int k = 0; k < HID; ++k) {
    const float zk = z1s[nl][k];
    const float4 w = *(const float4*)&W2s[k][cq * 4];
    h0 = fmaf(zk, w.x, h0);
    h1 = fmaf(zk, w.y, h1);
    h2 = fmaf(zk, w.z, h2);
    h3 = fmaf(zk, w.w, h3);
  }

  if (v < nN) {
    const float dv = dinv[v];
    float4 o;
    o.x = h0 * dv; o.y = h1 * dv; o.z = h2 * dv; o.w = h3 * dv;
    out4[(size_t)v * 16 + cq] = o;
  }
}

// ---- layer-2 gather + epilogue (atomic-free; z2 written once per row) ----
__global__ __launch_bounds__(256) void k_gather4(const int* __restrict__ csr,
                                                 const int* __restrict__ row_lo,
                                                 const int* __restrict__ row_hi,
                                                 const float4* __restrict__ H4,
                                                 const float* __restrict__ dinv,
                                                 const float* __restrict__ b,
                                                 float4* __restrict__ out4, int nN) {
  const int t = threadIdx.x;
  const int wid = t >> 6;
  const int lane = t & 63;
  const int ng = lane >> 4;
  const int cq = lane & 15;
  const int v = blockIdx.x * 16 + wid * 4 + ng;
  const int vv = min(v, nN - 1);
  const int lo = row_lo[vv];
  const int cnt = row_hi[vv] - lo;

  double acc[4][4];
#pragma unroll
  for (int c = 0; c < 4; ++c)
#pragma unroll
    for (int q = 0; q < 4; ++q) acc[c][q] = 0.0;
  {
    const float4 sv = H4[(size_t)vv * 16 + cq];
    acc[0][0] = (double)sv.x; acc[0][1] = (double)sv.y;
    acc[0][2] = (double)sv.z; acc[0][3] = (double)sv.w;
  }

  GATHER_ACC_LOOP

  if (v < nN) {
    const float dv = dinv[v];
    const float4 bb = ((const float4*)b)[cq];
    float4 o;
    o.x = fmaxf(fmaf(dv, (float)((acc[0][0] + acc[1][0]) + (acc[2][0] + acc[3][0])), bb.x), 0.f);
    o.y = fmaxf(fmaf(dv, (float)((acc[0][1] + acc[1][1]) + (acc[2][1] + acc[3][1])), bb.y), 0.f);
    o.z = fmaxf(fmaf(dv, (float)((acc[0][2] + acc[1][2]) + (acc[2][2] + acc[3][2])), bb.z), 0.f);
    o.w = fmaxf(fmaf(dv, (float)((acc[0][3] + acc[1][3]) + (acc[2][3] + acc[3][3])), bb.w), 0.f);
    out4[(size_t)v * 16 + cq] = o;
  }
}

// ---- pooling + head, atomic-free (batch is sorted): one block per graph ----
__device__ inline int lowerb(const int* __restrict__ a, int n, int key) {
  int lo = 0, hi = n;
  while (lo < hi) {
    int mid = (lo + hi) >> 1;
    if (a[mid] < key) lo = mid + 1; else hi = mid;
  }
  return lo;
}

__global__ __launch_bounds__(256) void k_pool_head(const float* __restrict__ Z,
                                                   const int* __restrict__ batch, int nN,
                                                   const float* __restrict__ Wl,
                                                   const float* __restrict__ bl,
                                                   float* __restrict__ out) {
  int g = blockIdx.x;
  int lane = threadIdx.x & 63;
  int wid = threadIdx.x >> 6;
  int lo = lowerb(batch, nN, g);
  int hi = lowerb(batch, nN, g + 1);
  double acc = 0.0;
  for (int r = lo + wid; r < hi; r += 4) acc += (double)Z[(size_t)r * HID + lane];
  __shared__ double s[4][HID];
  s[wid][lane] = acc;
  __syncthreads();
  if (wid == 0) {
    double tot = (s[0][lane] + s[1][lane]) + (s[2][lane] + s[3][lane]);
    double mean = tot / (double)max(hi - lo, 1);
    double p0 = mean * (double)Wl[lane * 2 + 0];
    double p1 = mean * (double)Wl[lane * 2 + 1];
#pragma unroll
    for (int off = 32; off; off >>= 1) {
      p0 += __shfl_xor(p0, off, 64);
      p1 += __shfl_xor(p1, off, 64);
    }
    if (lane == 0) {
      out[g * 2 + 0] = (float)(p0 + (double)bl[0]);
      out[g * 2 + 1] = (float)(p1 + (double)bl[1]);
    }
  }
}

extern "C" void kernel_launch(void* const* d_in, const int* in_sizes, int n_in,
                              void* d_out, int out_size, void* d_ws, size_t ws_size,
                              hipStream_t stream) {
  const float* x     = (const float*)d_in[0];
  const int*   ei    = (const int*)d_in[1];
  const int*   batch = (const int*)d_in[2];
  const float* W1    = (const float*)d_in[3];
  const float* b1    = (const float*)d_in[4];
  const float* W2    = (const float*)d_in[5];
  const float* b2    = (const float*)d_in[6];
  const float* Wl    = (const float*)d_in[7];
  const float* bl    = (const float*)d_in[8];
  float* out = (float*)d_out;

  const int nN = in_sizes[2];          // 50000
  const int nE = in_sizes[1] / 2;      // 800000
  const int nG = out_size / 2;         // 512
  const int* src = ei;
  const int* dst = ei + nE;

  char* ws = (char*)d_ws;
  size_t off = 0;
  auto alloc = [&](size_t bytes) {
    char* p = ws + off;
    off += (bytes + 255) & ~(size_t)255;
    return p;
  };
  int*   bcursor = (int*)alloc(MAXBUCK * 4);
  int*   row_lo  = (int*)alloc((size_t)nN * 4);
  int*   row_hi  = (int*)alloc((size_t)nN * 4);
  int*   csr     = (int*)alloc((size_t)MAXBUCK * CAP * 4);
  float* dinv    = (float*)alloc((size_t)nN * 4);
  float* A       = (float*)alloc((size_t)nN * HID * 4);
  float* B       = (float*)alloc((size_t)nN * HID * 4);
  int2*  pairs   = (int2*)A;           // aliases A: consumed before mm1 writes A

  const int nBuck = (nN + NPB - 1) / NPB;   // 391 buckets

  // CSR build
  hipMemsetAsync(bcursor, 0, MAXBUCK * 4, stream);
  k_bucket<<<(nE + CHUNK - 1) / CHUNK, 256, 0, stream>>>(src, dst, nE, bcursor, pairs, nBuck);
  k_place<<<nBuck, 256, 0, stream>>>(pairs, bcursor, csr, row_lo, row_hi, dinv, nN);

  // layer 1 matmul: A = dinv * (x @ W1)
  k_mm_tile<128><<<(nN + RB - 1) / RB, 256, 0, stream>>>(x, W1, dinv, A, nN);

  // fused layer-1 aggregation + mm2: B = dinv * (relu(dinv*agg(A)+b1) @ W2)
  k_gather_mm<<<(nN + 15) / 16, 256, 0, stream>>>(csr, row_lo, row_hi, (const float4*)A,
                                                  dinv, b1, W2, (float4*)B, nN);

  // layer 2 aggregation: A = relu(dinv*agg(B)+b2)
  k_gather4<<<(nN + 15) / 16, 256, 0, stream>>>(csr, row_lo, row_hi, (const float4*)B,
                                                dinv, b2, (float4*)A, nN);

  // pooling + head
  k_pool_head<<<nG, 256, 0, stream>>>(A, batch, nN, Wl, bl, out);
}

// Round 13
// 139.477 us; speedup vs baseline: 1.5123x; 1.5123x over previous
//
#include <hip/hip_runtime.h>

constexpr int HID = 64;
constexpr int RB = 128;        // mm block row-tile
constexpr int KC = 32;         // mm K-chunk
constexpr int NPB = 128;       // nodes per bucket (pow2: bucket = dst >> 7)
constexpr int MAXBUCK = 512;   // supports nN <= 65536
constexpr int CAP = 2560;      // pair slots per bucket (mean 2048 + 11 sigma)
constexpr int CHUNK = 2048;    // edges per k_bucket block (391 blocks)

// ---- CSR build pass 1: append (src,dst) pairs into fixed-capacity bucket
// regions. Block-level LDS histogram + one global reservation per
// (block,bucket) keeps each reserved range single-owner -> coalesced. ----
__global__ __launch_bounds__(256) void k_bucket(const int* __restrict__ src,
                                                const int* __restrict__ dst, int nE,
                                                int* __restrict__ bcursor,
                                                int2* __restrict__ pairs, int nBuck) {
  __shared__ int hist[MAXBUCK];
  __shared__ int base[MAXBUCK];
  const int t = threadIdx.x;
  const int e0 = blockIdx.x * CHUNK;
  const int eEnd = min(e0 + CHUNK, nE);
  for (int i = t; i < nBuck; i += 256) hist[i] = 0;
  __syncthreads();
  for (int e = e0 + t; e < eEnd; e += 256)
    atomicAdd(&hist[dst[e] >> 7], 1);
  __syncthreads();
  for (int i = t; i < nBuck; i += 256) {
    int c = hist[i];
    int r = (c > 0) ? atomicAdd(&bcursor[i], c) : 0;
    base[i] = i * CAP + r;
    hist[i] = 0;
  }
  __syncthreads();
  for (int e = e0 + t; e < eEnd; e += 256) {
    int d = dst[e];
    int b = d >> 7;
    int idx = atomicAdd(&hist[b], 1);
    pairs[base[b] + idx] = make_int2(src[e], d);
  }
}

// ---- CSR build pass 2: one block per bucket. LDS histogram -> per-node deg,
// LDS scan -> row bounds + dinv, then local scatter of csr. ----
__global__ __launch_bounds__(256) void k_place(const int2* __restrict__ pairs,
                                               const int* __restrict__ bcursor,
                                               int* __restrict__ csr,
                                               int* __restrict__ row_lo,
                                               int* __restrict__ row_hi,
                                               float* __restrict__ dinv, int nN) {
  __shared__ int cnt[NPB], sc[NPB], cur[NPB];
  const int t = threadIdx.x;
  const int b = blockIdx.x;
  const int vbase = b * NPB;
  const int lo = b * CAP;
  const int npairs = bcursor[b];
  if (t < NPB) cnt[t] = 0;
  __syncthreads();
  for (int p = t; p < npairs; p += 256)
    atomicAdd(&cnt[pairs[lo + p].y - vbase], 1);
  __syncthreads();
  if (t < NPB) sc[t] = cnt[t];
  __syncthreads();
  for (int d = 1; d < NPB; d <<= 1) {
    int x = 0;
    if (t < NPB) { x = sc[t]; if (t >= d) x += sc[t - d]; }
    __syncthreads();
    if (t < NPB) sc[t] = x;
    __syncthreads();
  }
  if (t < NPB && vbase + t < nN) {
    int ex = sc[t] - cnt[t];
    row_lo[vbase + t] = lo + ex;
    row_hi[vbase + t] = lo + sc[t];
    dinv[vbase + t] = rsqrtf((float)cnt[t] + 1.0f);   // +1 = self-loop
    cur[t] = lo + ex;
  }
  __syncthreads();
  for (int p = t; p < npairs; p += 256) {
    int2 e = pairs[lo + p];
    int pos = atomicAdd(&cur[e.y - vbase], 1);
    csr[pos] = e.x;
  }
}

// ---- LDS-tiled matmul + row scale: out[v,c] = dinv[v] * sum_k X[v,k]*W[k,c] ----
template <int K>
__global__ __launch_bounds__(256) void k_mm_tile(const float* __restrict__ X,
                                                 const float* __restrict__ W,
                                                 const float* __restrict__ dinv,
                                                 float* __restrict__ out, int nRows) {
  __shared__ float Xs[RB][KC + 1];
  __shared__ float Ws[KC][HID];

  const int t    = threadIdx.x;
  const int lane = t & 63;
  const int wid  = t >> 6;
  const int rg   = lane >> 3;
  const int cg   = lane & 7;
  const int rb   = blockIdx.x * RB;
  const int rloc = wid * 32 + rg * 4;

  float acc[4][8];
#pragma unroll
  for (int i = 0; i < 4; ++i)
#pragma unroll
    for (int j = 0; j < 8; ++j) acc[i][j] = 0.f;

  for (int c = 0; c < K / KC; ++c) {
    const int k0 = c * KC;
    {
      const int r  = t >> 1;
      const int kh = (t & 1) * 16;
      const int grow = rb + r;
      if (grow < nRows) {
        const float* p = X + (size_t)grow * K + k0 + kh;
#pragma unroll
        for (int q = 0; q < 4; ++q) {
          const float4 v = *(const float4*)(p + q * 4);
          float* d = &Xs[r][kh + q * 4];
          d[0] = v.x; d[1] = v.y; d[2] = v.z; d[3] = v.w;
        }
      }
    }
    {
      const float* p = W + (size_t)(k0 + (t >> 3)) * HID + (t & 7) * 8;
      const float4 v0 = *(const float4*)p;
      const float4 v1 = *(const float4*)(p + 4);
      float* d = &Ws[t >> 3][(t & 7) * 8];
      ((float4*)d)[0] = v0;
      ((float4*)d)[1] = v1;
    }
    __syncthreads();

#pragma unroll
    for (int k = 0; k < KC; ++k) {
      const float4 w0 = *(const float4*)&Ws[k][cg * 8];
      const float4 w1 = *(const float4*)&Ws[k][cg * 8 + 4];
      float xv[4];
#pragma unroll
      for (int i = 0; i < 4; ++i) xv[i] = Xs[rloc + i][k];
#pragma unroll
      for (int i = 0; i < 4; ++i) {
        acc[i][0] = fmaf(xv[i], w0.x, acc[i][0]);
        acc[i][1] = fmaf(xv[i], w0.y, acc[i][1]);
        acc[i][2] = fmaf(xv[i], w0.z, acc[i][2]);
        acc[i][3] = fmaf(xv[i], w0.w, acc[i][3]);
        acc[i][4] = fmaf(xv[i], w1.x, acc[i][4]);
        acc[i][5] = fmaf(xv[i], w1.y, acc[i][5]);
        acc[i][6] = fmaf(xv[i], w1.z, acc[i][6]);
        acc[i][7] = fmaf(xv[i], w1.w, acc[i][7]);
      }
    }
    __syncthreads();
  }

#pragma unroll
  for (int i = 0; i < 4; ++i) {
    const int row = rb + rloc + i;
    if (row < nRows) {
      const float s = dinv[row];
      float4 o0, o1;
      o0.x = acc[i][0] * s; o0.y = acc[i][1] * s; o0.z = acc[i][2] * s; o0.w = acc[i][3] * s;
      o1.x = acc[i][4] * s; o1.y = acc[i][5] * s; o1.z = acc[i][6] * s; o1.w = acc[i][7] * s;
      float* p = out + (size_t)row * HID + cg * 8;
      ((float4*)p)[0] = o0;
      ((float4*)p)[1] = o1;
    }
  }
}

// ---- fused gather + epilogue + 64x64 matmul (layer1 agg + mm2) ----
// 16 lanes per node, 4 nodes/wave, double-acc gather (order-insensitive),
// csr index prefetch, then z1 staged in LDS and multiplied by LDS-resident W2.
// NOTE: compiler-scheduled inner loop (VGPR ~32, occupancy ~55%) beats
// explicit 8-deep staging (VGPR 96, occupancy 17.5%, 2x slower) -- r12.
__global__ __launch_bounds__(256) void k_gather_mm(const int* __restrict__ csr,
                                                   const int* __restrict__ row_lo,
                                                   const int* __restrict__ row_hi,
                                                   const float4* __restrict__ H4,
                                                   const float* __restrict__ dinv,
                                                   const float* __restrict__ b,
                                                   const float* __restrict__ W2,
                                                   float4* __restrict__ out4, int nN) {
  __shared__ float W2s[HID][HID];     // 16 KB
  __shared__ float z1s[16][68];       // padded

  const int t = threadIdx.x;
  for (int i = t; i < HID * HID / 4; i += 256)
    ((float4*)W2s)[i] = ((const float4*)W2)[i];
  __syncthreads();

  const int wid = t >> 6;
  const int lane = t & 63;
  const int ng = lane >> 4;
  const int cq = lane & 15;
  const int nl = wid * 4 + ng;
  const int v = blockIdx.x * 16 + nl;
  const int vv = min(v, nN - 1);
  const int lo = row_lo[vv];
  const int cnt = row_hi[vv] - lo;

  double acc[4][4];
#pragma unroll
  for (int c = 0; c < 4; ++c)
#pragma unroll
    for (int q = 0; q < 4; ++q) acc[c][q] = 0.0;
  {
    const float4 sv = H4[(size_t)vv * 16 + cq];   // self-loop
    acc[0][0] = (double)sv.x; acc[0][1] = (double)sv.y;
    acc[0][2] = (double)sv.z; acc[0][3] = (double)sv.w;
  }

  int idxv = (cq < cnt) ? csr[lo + cq] : 0;
  for (int base = 0; base < cnt; base += 16) {
    const int nb = base + 16;
    int nidx = (nb + cq < cnt) ? csr[lo + nb + cq] : 0;   // prefetch next batch
#pragma unroll
    for (int j = 0; j < 16; ++j) {
      int s = __shfl(idxv, (ng << 4) + j, 64);
      if (base + j < cnt) {
        const float4 h = H4[(size_t)s * 16 + cq];
        acc[j & 3][0] += (double)h.x;
        acc[j & 3][1] += (double)h.y;
        acc[j & 3][2] += (double)h.z;
        acc[j & 3][3] += (double)h.w;
      }
    }
    idxv = nidx;
  }

  // z1 = relu(dinv*gather + b1) -> LDS (wave-internal, no barrier)
  {
    const float dv = dinv[vv];
    const float4 bb = ((const float4*)b)[cq];
    float4 z;
    z.x = fmaxf(fmaf(dv, (float)((acc[0][0] + acc[1][0]) + (acc[2][0] + acc[3][0])), bb.x), 0.f);
    z.y = fmaxf(fmaf(dv, (float)((acc[0][1] + acc[1][1]) + (acc[2][1] + acc[3][1])), bb.y), 0.f);
    z.z = fmaxf(fmaf(dv, (float)((acc[0][2] + acc[1][2]) + (acc[2][2] + acc[3][2])), bb.z), 0.f);
    z.w = fmaxf(fmaf(dv, (float)((acc[0][3] + acc[1][3]) + (acc[2][3] + acc[3][3])), bb.w), 0.f);
    float* zp = &z1s[nl][cq * 4];
    zp[0] = z.x; zp[1] = z.y; zp[2] = z.z; zp[3] = z.w;
  }

  float h0 = 0.f, h1 = 0.f, h2 = 0.f, h3 = 0.f;
#pragma unroll 8
  for (int k = 0; k < HID; ++k) {
    const float zk = z1s[nl][k];
    const float4 w = *(const float4*)&W2s[k][cq * 4];
    h0 = fmaf(zk, w.x, h0);
    h1 = fmaf(zk, w.y, h1);
    h2 = fmaf(zk, w.z, h2);
    h3 = fmaf(zk, w.w, h3);
  }

  if (v < nN) {
    const float dv = dinv[v];
    float4 o;
    o.x = h0 * dv; o.y = h1 * dv; o.z = h2 * dv; o.w = h3 * dv;
    out4[(size_t)v * 16 + cq] = o;
  }
}

// ---- layer-2 gather + epilogue (atomic-free; z2 written once per row) ----
__global__ __launch_bounds__(256) void k_gather4(const int* __restrict__ csr,
                                                 const int* __restrict__ row_lo,
                                                 const int* __restrict__ row_hi,
                                                 const float4* __restrict__ H4,
                                                 const float* __restrict__ dinv,
                                                 const float* __restrict__ b,
                                                 float4* __restrict__ out4, int nN) {
  const int t = threadIdx.x;
  const int wid = t >> 6;
  const int lane = t & 63;
  const int ng = lane >> 4;
  const int cq = lane & 15;
  const int v = blockIdx.x * 16 + wid * 4 + ng;
  const int vv = min(v, nN - 1);
  const int lo = row_lo[vv];
  const int cnt = row_hi[vv] - lo;

  double acc[4][4];
#pragma unroll
  for (int c = 0; c < 4; ++c)
#pragma unroll
    for (int q = 0; q < 4; ++q) acc[c][q] = 0.0;
  {
    const float4 sv = H4[(size_t)vv * 16 + cq];
    acc[0][0] = (double)sv.x; acc[0][1] = (double)sv.y;
    acc[0][2] = (double)sv.z; acc[0][3] = (double)sv.w;
  }

  int idxv = (cq < cnt) ? csr[lo + cq] : 0;
  for (int base = 0; base < cnt; base += 16) {
    const int nb = base + 16;
    int nidx = (nb + cq < cnt) ? csr[lo + nb + cq] : 0;   // prefetch next batch
#pragma unroll
    for (int j = 0; j < 16; ++j) {
      int s = __shfl(idxv, (ng << 4) + j, 64);
      if (base + j < cnt) {
        const float4 h = H4[(size_t)s * 16 + cq];
        acc[j & 3][0] += (double)h.x;
        acc[j & 3][1] += (double)h.y;
        acc[j & 3][2] += (double)h.z;
        acc[j & 3][3] += (double)h.w;
      }
    }
    idxv = nidx;
  }

  if (v < nN) {
    const float dv = dinv[v];
    const float4 bb = ((const float4*)b)[cq];
    float4 o;
    o.x = fmaxf(fmaf(dv, (float)((acc[0][0] + acc[1][0]) + (acc[2][0] + acc[3][0])), bb.x), 0.f);
    o.y = fmaxf(fmaf(dv, (float)((acc[0][1] + acc[1][1]) + (acc[2][1] + acc[3][1])), bb.y), 0.f);
    o.z = fmaxf(fmaf(dv, (float)((acc[0][2] + acc[1][2]) + (acc[2][2] + acc[3][2])), bb.z), 0.f);
    o.w = fmaxf(fmaf(dv, (float)((acc[0][3] + acc[1][3]) + (acc[2][3] + acc[3][3])), bb.w), 0.f);
    out4[(size_t)v * 16 + cq] = o;
  }
}

// ---- pooling + head, atomic-free (batch is sorted): one block per graph ----
__device__ inline int lowerb(const int* __restrict__ a, int n, int key) {
  int lo = 0, hi = n;
  while (lo < hi) {
    int mid = (lo + hi) >> 1;
    if (a[mid] < key) lo = mid + 1; else hi = mid;
  }
  return lo;
}

__global__ __launch_bounds__(256) void k_pool_head(const float* __restrict__ Z,
                                                   const int* __restrict__ batch, int nN,
                                                   const float* __restrict__ Wl,
                                                   const float* __restrict__ bl,
                                                   float* __restrict__ out) {
  int g = blockIdx.x;
  int lane = threadIdx.x & 63;
  int wid = threadIdx.x >> 6;
  int lo = lowerb(batch, nN, g);
  int hi = lowerb(batch, nN, g + 1);
  double acc = 0.0;
  for (int r = lo + wid; r < hi; r += 4) acc += (double)Z[(size_t)r * HID + lane];
  __shared__ double s[4][HID];
  s[wid][lane] = acc;
  __syncthreads();
  if (wid == 0) {
    double tot = (s[0][lane] + s[1][lane]) + (s[2][lane] + s[3][lane]);
    double mean = tot / (double)max(hi - lo, 1);
    double p0 = mean * (double)Wl[lane * 2 + 0];
    double p1 = mean * (double)Wl[lane * 2 + 1];
#pragma unroll
    for (int off = 32; off; off >>= 1) {
      p0 += __shfl_xor(p0, off, 64);
      p1 += __shfl_xor(p1, off, 64);
    }
    if (lane == 0) {
      out[g * 2 + 0] = (float)(p0 + (double)bl[0]);
      out[g * 2 + 1] = (float)(p1 + (double)bl[1]);
    }
  }
}

extern "C" void kernel_launch(void* const* d_in, const int* in_sizes, int n_in,
                              void* d_out, int out_size, void* d_ws, size_t ws_size,
                              hipStream_t stream) {
  const float* x     = (const float*)d_in[0];
  const int*   ei    = (const int*)d_in[1];
  const int*   batch = (const int*)d_in[2];
  const float* W1    = (const float*)d_in[3];
  const float* b1    = (const float*)d_in[4];
  const float* W2    = (const float*)d_in[5];
  const float* b2    = (const float*)d_in[6];
  const float* Wl    = (const float*)d_in[7];
  const float* bl    = (const float*)d_in[8];
  float* out = (float*)d_out;

  const int nN = in_sizes[2];          // 50000
  const int nE = in_sizes[1] / 2;      // 800000
  const int nG = out_size / 2;         // 512
  const int* src = ei;
  const int* dst = ei + nE;

  char* ws = (char*)d_ws;
  size_t off = 0;
  auto alloc = [&](size_t bytes) {
    char* p = ws + off;
    off += (bytes + 255) & ~(size_t)255;
    return p;
  };
  int*   bcursor = (int*)alloc(MAXBUCK * 4);
  int*   row_lo  = (int*)alloc((size_t)nN * 4);
  int*   row_hi  = (int*)alloc((size_t)nN * 4);
  int*   csr     = (int*)alloc((size_t)MAXBUCK * CAP * 4);
  float* dinv    = (float*)alloc((size_t)nN * 4);
  float* A       = (float*)alloc((size_t)nN * HID * 4);
  float* B       = (float*)alloc((size_t)nN * HID * 4);
  int2*  pairs   = (int2*)A;           // aliases A: consumed before mm1 writes A

  const int nBuck = (nN + NPB - 1) / NPB;   // 391 buckets

  // CSR build
  hipMemsetAsync(bcursor, 0, MAXBUCK * 4, stream);
  k_bucket<<<(nE + CHUNK - 1) / CHUNK, 256, 0, stream>>>(src, dst, nE, bcursor, pairs, nBuck);
  k_place<<<nBuck, 256, 0, stream>>>(pairs, bcursor, csr, row_lo, row_hi, dinv, nN);

  // layer 1 matmul: A = dinv * (x @ W1)
  k_mm_tile<128><<<(nN + RB - 1) / RB, 256, 0, stream>>>(x, W1, dinv, A, nN);

  // fused layer-1 aggregation + mm2: B = dinv * (relu(dinv*agg(A)+b1) @ W2)
  k_gather_mm<<<(nN + 15) / 16, 256, 0, stream>>>(csr, row_lo, row_hi, (const float4*)A,
                                                  dinv, b1, W2, (float4*)B, nN);

  // layer 2 aggregation: A = relu(dinv*agg(B)+b2)
  k_gather4<<<(nN + 15) / 16, 256, 0, stream>>>(csr, row_lo, row_hi, (const float4*)B,
                                                dinv, b2, (float4*)A, nN);

  // pooling + head
  k_pool_head<<<nG, 256, 0, stream>>>(A, batch, nN, Wl, bl, out);
}